// Round 9
// baseline (61.023 us; speedup 1.0000x reference)
//
#include <hip/hip_runtime.h>
#include <math.h>

#define HIDDEN 128
#define NGRAPH 16384
#define GPB 32                  // graphs per block
#define NBLK (NGRAPH / GPB)     // 512 blocks
#define NTHR 512                // 8 waves/block; 2 blocks/CU = 16 waves/CU

typedef __attribute__((ext_vector_type(8))) short short8;   // 8 bf16
typedef __attribute__((ext_vector_type(4))) float f32x4;    // MFMA accum

// shifted-softplus shift = log(2)
__device__ __constant__ float kSHIFT = 0.69314718055994530942f;

// fp32 -> bf16 (RNE), bit-level
__device__ __forceinline__ unsigned short f2bf(float f) {
    unsigned int u = __builtin_bit_cast(unsigned int, f);
    u = (u + 0x7FFFu + ((u >> 16) & 1u)) >> 16;
    return (unsigned short)u;
}

// ---------------------------------------------------------------------------
// Single fused kernel: 512 blocks x 512 threads (8 waves), 32 graphs/block.
// - No offsets kernel: each wave binary-searches its own 5 segment offsets
//   (lanes 0-4, L2-hot batch, overlapped with B-frag loads), reads them via
//   __shfl. No pre-phase-1 barrier, no workspace.
// - B-frags: each wave owns a 32-col stripe of W1, loaded once into registers
//   as bf16 (issued before the search so the VMEM latency hides under it).
// - Phase 1: wave streams the contiguous rows of its 4 graphs; 64 lanes cover
//   a row as float2; 8 rows per straight-line load block (8 loads in flight);
//   wave-uniform boundary flushes convert to bf16 and store XOR-swizzled
//   rows into u_b LDS.
// - Phase 2: 16 x v_mfma_f32_16x16x32_bf16 per wave; conflict-free swizzled
//   ds_read_b128 A-frags. Epilogue: bias -> shifted softplus -> *W2 ->
//   16-lane shfl reduce -> cross-wave LDS reduce -> out.
// LDS: 8 KB u_b + 1 KB red. VGPR ~90 -> fits __launch_bounds__(512,4).
// ---------------------------------------------------------------------------
__global__ __launch_bounds__(NTHR, 4) void fused_kernel(
    const float* __restrict__ v, const int* __restrict__ batch,
    const float* __restrict__ W1, const float* __restrict__ b1,
    const float* __restrict__ W2, const float* __restrict__ b2,
    float* __restrict__ out, int n_nodes)
{
    __shared__ short u_b[GPB * HIDDEN];    // 8 KB, bf16, k XOR-swizzled per row
    __shared__ float red_s[8][GPB];        // 1 KB

    const int t  = threadIdx.x;
    const int l  = t & 63;
    const int w  = t >> 6;                 // wave id 0..7
    const int g0 = blockIdx.x * GPB;
    const int w4 = w * 4;                  // this wave's first local graph

    // ---- B-fragments: W1 cols [w*32, w*32+32), bf16, registers ----
    // Issued FIRST so their latency hides under the offset search.
    // frag[ct][kt]: lane l holds B[k = kt*32+(l>>4)*8+j][col = w*32+ct*16+(l&15)]
    short8 bfrag[2][4];
    {
        const int lcol = w * 32 + (l & 15);
        #pragma unroll
        for (int ct = 0; ct < 2; ++ct) {
            const int col = lcol + ct * 16;
            #pragma unroll
            for (int kt = 0; kt < 4; ++kt) {
                const int k0 = kt * 32 + (l >> 4) * 8;
                short8 f;
                #pragma unroll
                for (int j = 0; j < 8; ++j)
                    f[j] = (short)f2bf(W1[(size_t)(k0 + j) * 256 + col]);
                bfrag[ct][kt] = f;
            }
        }
    }

    // ---- per-wave segment offsets: lanes 0..4 lower_bound(batch, g0+w4+l) ----
    int oreg = 0;
    if (l < 5) {
        const int target = g0 + w4 + l;
        int slo = 0, shi = n_nodes;
        while (slo < shi) {
            int mid = (slo + shi) >> 1;
            if (batch[mid] < target) slo = mid + 1; else shi = mid;
        }
        oreg = slo;
    }
    const int lo = __shfl(oreg, 0);
    const int hi = __shfl(oreg, 4);

    // ---------------- Phase 1: continuous segment-sum stream ----------------
    const float2* __restrict__ v2 = reinterpret_cast<const float2*>(v);
    int cur = 0;
    int bnd = __shfl(oreg, 1);
    float accx = 0.f, accy = 0.f;
    const int k2 = 2 * l;                  // lane's k-pair base

    for (int r = lo; r < hi; r += 8) {
        float2 x[8];
        #pragma unroll
        for (int q = 0; q < 8; ++q) {
            int rq = r + q;
            rq = (rq < hi) ? rq : (hi - 1);          // clamp tail (uniform)
            x[q] = v2[(size_t)rq * 64 + l];
        }
        #pragma unroll
        for (int q = 0; q < 8; ++q) {
            if (r + q < hi) {
                while (r + q >= bnd) {               // taken ~1 in 30 rows
                    const int row = w4 + cur;
                    const int idx = row * HIDDEN + (k2 ^ ((row & 7) * 8));
                    unsigned int pk = (unsigned int)f2bf(accx)
                                    | ((unsigned int)f2bf(accy) << 16);
                    *reinterpret_cast<unsigned int*>(&u_b[idx]) = pk;
                    accx = 0.f; accy = 0.f;
                    ++cur;
                    bnd = __shfl(oreg, cur + 1);     // lane idx <= 4
                }
                accx += x[q].x; accy += x[q].y;
            }
        }
    }
    while (cur < 4) {                                 // flush last + empties
        const int row = w4 + cur;
        const int idx = row * HIDDEN + (k2 ^ ((row & 7) * 8));
        unsigned int pk = (unsigned int)f2bf(accx)
                        | ((unsigned int)f2bf(accy) << 16);
        *reinterpret_cast<unsigned int*>(&u_b[idx]) = pk;
        accx = 0.f; accy = 0.f;
        ++cur;
    }
    __syncthreads();

    // ---------------- Phase 2: MFMA MLP ----------------
    f32x4 acc[2][2];                       // [row-tile][col-tile]
    #pragma unroll
    for (int rt = 0; rt < 2; ++rt)
        #pragma unroll
        for (int ct = 0; ct < 2; ++ct)
            acc[rt][ct] = (f32x4){0.f, 0.f, 0.f, 0.f};

    #pragma unroll
    for (int kt = 0; kt < 4; ++kt) {
        #pragma unroll
        for (int rt = 0; rt < 2; ++rt) {
            const int row = rt * 16 + (l & 15);
            const int k0  = kt * 32 + (l >> 4) * 8;
            short8 a = *reinterpret_cast<const short8*>(
                &u_b[row * HIDDEN + (k0 ^ ((row & 7) * 8))]);
            #pragma unroll
            for (int ct = 0; ct < 2; ++ct)
                acc[rt][ct] = __builtin_amdgcn_mfma_f32_16x16x32_bf16(
                    a, bfrag[ct][kt], acc[rt][ct], 0, 0, 0);
        }
    }

    // epilogue: bias -> shifted softplus -> *W2 -> reduce 16 cols -> LDS
    float b1c[2], w2c[2];
    #pragma unroll
    for (int ct = 0; ct < 2; ++ct) {
        const int col = w * 32 + ct * 16 + (l & 15);
        b1c[ct] = b1[col];
        w2c[ct] = W2[col];
    }
    #pragma unroll
    for (int rt = 0; rt < 2; ++rt) {
        float p[4] = {0.f, 0.f, 0.f, 0.f};
        #pragma unroll
        for (int ct = 0; ct < 2; ++ct)
            #pragma unroll
            for (int reg = 0; reg < 4; ++reg) {
                float x = acc[rt][ct][reg] + b1c[ct];
                float h = fmaxf(x, 0.f) + log1pf(expf(-fabsf(x))) - kSHIFT;
                p[reg] = fmaf(h, w2c[ct], p[reg]);
            }
        #pragma unroll
        for (int reg = 0; reg < 4; ++reg) {
            float s = p[reg];
            s += __shfl_xor(s, 1);
            s += __shfl_xor(s, 2);
            s += __shfl_xor(s, 4);
            s += __shfl_xor(s, 8);
            if ((l & 15) == 0)
                red_s[w][rt * 16 + (l >> 4) * 4 + reg] = s;
        }
    }
    __syncthreads();

    if (t < GPB) {
        float s = (red_s[0][t] + red_s[1][t]) + (red_s[2][t] + red_s[3][t])
                + (red_s[4][t] + red_s[5][t]) + (red_s[6][t] + red_s[7][t]);
        out[g0 + t] = s + b2[0];
    }
}

extern "C" void kernel_launch(void* const* d_in, const int* in_sizes, int n_in,
                              void* d_out, int out_size, void* d_ws, size_t ws_size,
                              hipStream_t stream) {
    const float* v     = (const float*)d_in[0];
    const int*   batch = (const int*)d_in[1];
    const float* W1    = (const float*)d_in[2];
    const float* b1    = (const float*)d_in[3];
    const float* W2    = (const float*)d_in[4];
    const float* b2    = (const float*)d_in[5];
    float* out = (float*)d_out;

    const int n_nodes = in_sizes[0] / HIDDEN;   // 500000

    fused_kernel<<<NBLK, NTHR, 0, stream>>>(v, batch, W1, b1, W2, b2, out, n_nodes);
}